// Round 1
// baseline (1860.430 us; speedup 1.0000x reference)
//
#include <hip/hip_runtime.h>
#include <hip/hip_bf16.h>

#define TT 20
#define BB 64
#define SS 64
#define HH 512
#define EE 512
#define VV 32000

typedef __bf16 bf16x8 __attribute__((ext_vector_type(8)));
typedef float f32x4 __attribute__((ext_vector_type(4)));

// ---------------- elementwise helpers ----------------

__global__ __launch_bounds__(256) void f2bf_kernel(const float* __restrict__ in,
                                                   __hip_bfloat16* __restrict__ out, int n) {
    int i = blockIdx.x * 256 + threadIdx.x;
    if (i < n) out[i] = __float2bfloat16(in[i]);
}

__global__ __launch_bounds__(256) void zero_h_kernel(float* __restrict__ hf,
                                                     __hip_bfloat16* __restrict__ hb, int n) {
    int i = blockIdx.x * 256 + threadIdx.x;
    if (i < n) { hf[i] = 0.f; hb[i] = __float2bfloat16(0.f); }
}

// xs[t][b][e] = embed_table[captions[b][t]][e], stored bf16 at (t*64+b)*512+e
__global__ __launch_bounds__(256) void gather_emb_kernel(const float* __restrict__ tab,
                                                         const int* __restrict__ cap,
                                                         __hip_bfloat16* __restrict__ out) {
    int i = blockIdx.x * 256 + threadIdx.x;  // T*B*E total
    int e = i & (EE - 1);
    int tb = i >> 9;          // t*64 + b
    int t = tb >> 6;
    int b = tb & 63;
    int tok = cap[b * TT + t];
    out[i] = __float2bfloat16(tab[(size_t)tok * EE + e]);
}

// ---------------- generic TN GEMM: C[M,N] = A[M,K] * B[N,K]^T (+bias) ----------------
// bf16 inputs, fp32 MFMA accumulate. Block = 256 thr = 4 waves (2x2), block tile 64x64,
// wave tile 32x32 (2x2 frags of 16x16), K step 32. All dims assumed divisible.
// Output row remap: off = (row*row_stride + row_off)*ldc + col  (+ z*sCz).

__global__ __launch_bounds__(256) void gemm_bt_kernel(
    const __hip_bfloat16* __restrict__ A,
    const __hip_bfloat16* __restrict__ Bm,
    const float* __restrict__ bias,
    float* __restrict__ Cf,
    __hip_bfloat16* __restrict__ Cb,
    int K, int ldc, int row_stride, int row_off,
    long sAz, long sBz, long sCz)
{
    A  += (size_t)blockIdx.z * sAz;
    Bm += (size_t)blockIdx.z * sBz;
    long cbase = (long)blockIdx.z * sCz;

    int m0 = blockIdx.x * 64, n0 = blockIdx.y * 64;
    int wave = threadIdx.x >> 6, lane = threadIdx.x & 63;
    int wm = wave & 1, wn = wave >> 1;
    int row16 = lane & 15, quad = lane >> 4;

    const __hip_bfloat16* a0p = A  + (size_t)(m0 + wm * 32 + row16) * K + quad * 8;
    const __hip_bfloat16* a1p = a0p + (size_t)16 * K;
    const __hip_bfloat16* b0p = Bm + (size_t)(n0 + wn * 32 + row16) * K + quad * 8;
    const __hip_bfloat16* b1p = b0p + (size_t)16 * K;

    f32x4 acc00 = {0.f, 0.f, 0.f, 0.f};
    f32x4 acc01 = {0.f, 0.f, 0.f, 0.f};
    f32x4 acc10 = {0.f, 0.f, 0.f, 0.f};
    f32x4 acc11 = {0.f, 0.f, 0.f, 0.f};

    for (int k = 0; k < K; k += 32) {
        bf16x8 a0 = *reinterpret_cast<const bf16x8*>(a0p + k);
        bf16x8 a1 = *reinterpret_cast<const bf16x8*>(a1p + k);
        bf16x8 b0 = *reinterpret_cast<const bf16x8*>(b0p + k);
        bf16x8 b1 = *reinterpret_cast<const bf16x8*>(b1p + k);
        acc00 = __builtin_amdgcn_mfma_f32_16x16x32_bf16(a0, b0, acc00, 0, 0, 0);
        acc01 = __builtin_amdgcn_mfma_f32_16x16x32_bf16(a0, b1, acc01, 0, 0, 0);
        acc10 = __builtin_amdgcn_mfma_f32_16x16x32_bf16(a1, b0, acc10, 0, 0, 0);
        acc11 = __builtin_amdgcn_mfma_f32_16x16x32_bf16(a1, b1, acc11, 0, 0, 0);
    }

    f32x4 accs[2][2] = {{acc00, acc01}, {acc10, acc11}};
#pragma unroll
    for (int mt = 0; mt < 2; ++mt) {
#pragma unroll
        for (int nt = 0; nt < 2; ++nt) {
            int col = n0 + wn * 32 + nt * 16 + row16;
            float bv = bias ? bias[col] : 0.f;
#pragma unroll
            for (int r = 0; r < 4; ++r) {
                int row = m0 + wm * 32 + mt * 16 + quad * 4 + r;
                long off = cbase + (long)(row * row_stride + row_off) * ldc + col;
                float v = accs[mt][nt][r] + bv;
                if (Cb) Cb[off] = __float2bfloat16(v);
                else    Cf[off] = v;
            }
        }
    }
}

// ---------------- GRU gate combine ----------------

__device__ inline float sigmf(float x) { return 1.f / (1.f + __expf(-x)); }

// GI, GH: 64 x 1536 fp32 (no biases). h, hb: 64 x 512. 32768 threads.
__global__ __launch_bounds__(256) void gru_combine_kernel(
    const float* __restrict__ GI, const float* __restrict__ GH,
    const float* __restrict__ bih, const float* __restrict__ bhh,
    float* __restrict__ h, __hip_bfloat16* __restrict__ hb)
{
    int i = blockIdx.x * 256 + threadIdx.x;  // 0..32767
    int b = i >> 9, j = i & 511;
    const float* gi = GI + (size_t)b * 1536;
    const float* gh = GH + (size_t)b * 1536;
    float ir = gi[j]        + bih[j];
    float iz = gi[j + 512]  + bih[j + 512];
    float in_ = gi[j + 1024] + bih[j + 1024];
    float hr = gh[j]        + bhh[j];
    float hz = gh[j + 512]  + bhh[j + 512];
    float hn = gh[j + 1024] + bhh[j + 1024];
    float r = sigmf(ir + hr);
    float z = sigmf(iz + hz);
    float n = tanhf(in_ + r * hn);
    float hv = h[i];
    float hnew = (1.f - z) * n + z * hv;
    h[i] = hnew;
    hb[i] = __float2bfloat16(hnew);
}

// ---------------- attention (one wave per (b, head)) ----------------
// q: 64x512 fp32 (bias already added). KV: 4096 x 1024 fp32 (cols 0:512 K, 512:1024 V).
__global__ __launch_bounds__(64) void attn_kernel(
    const float* __restrict__ q, const float* __restrict__ KV,
    __hip_bfloat16* __restrict__ ctxb)
{
    int b = blockIdx.x >> 3, nh = blockIdx.x & 7;
    int lane = threadIdx.x;

    const float* qrow = q + (size_t)b * HH + nh * 64;
    const float* kr   = KV + (size_t)(b * 64 + lane) * 1024 + nh * 64;
    float sc = 0.f;
#pragma unroll
    for (int d = 0; d < 64; ++d) sc += qrow[d] * kr[d];
    sc *= 0.125f;  // 1/sqrt(64)

    float m = sc;
    for (int off = 32; off; off >>= 1) m = fmaxf(m, __shfl_xor(m, off, 64));
    float e = __expf(sc - m);
    float s = e;
    for (int off = 32; off; off >>= 1) s += __shfl_xor(s, off, 64);
    float p = e / s;

    __shared__ float pl[64];
    pl[lane] = p;
    __syncthreads();

    float acc = 0.f;
    const float* vb = KV + (size_t)(b * 64) * 1024 + 512 + nh * 64 + lane;
#pragma unroll
    for (int si = 0; si < 64; ++si) acc += pl[si] * vb[(size_t)si * 1024];

    ctxb[(size_t)b * HH + nh * 64 + lane] = __float2bfloat16(acc);
}

// ---------------- host ----------------

extern "C" void kernel_launch(void* const* d_in, const int* in_sizes, int n_in,
                              void* d_out, int out_size, void* d_ws, size_t ws_size,
                              hipStream_t stream) {
    const float* enc        = (const float*)d_in[0];
    const int*   cap        = (const int*)d_in[1];
    const float* emb_tab    = (const float*)d_in[2];
    const float* w_ih       = (const float*)d_in[3];
    const float* w_hh       = (const float*)d_in[4];
    const float* b_ih       = (const float*)d_in[5];
    const float* b_hh       = (const float*)d_in[6];
    const float* in_proj_w  = (const float*)d_in[7];
    const float* in_proj_b  = (const float*)d_in[8];
    const float* out_proj_w = (const float*)d_in[9];
    const float* out_proj_b = (const float*)d_in[10];
    const float* fc_w       = (const float*)d_in[11];
    const float* fc_b       = (const float*)d_in[12];
    float* out = (float*)d_out;

    char* p = (char*)d_ws;
    auto alloc = [&](size_t bytes) {
        char* r = p;
        p += (bytes + 255) & ~(size_t)255;
        return r;
    };
    __hip_bfloat16* fcw_bf  = (__hip_bfloat16*)alloc((size_t)VV * HH * 2);
    __hip_bfloat16* enc_bf  = (__hip_bfloat16*)alloc((size_t)BB * SS * HH * 2);
    __hip_bfloat16* inp_bf  = (__hip_bfloat16*)alloc((size_t)1536 * 512 * 2);
    __hip_bfloat16* wih_bf  = (__hip_bfloat16*)alloc((size_t)3 * 1536 * 512 * 2);
    __hip_bfloat16* whh_bf  = (__hip_bfloat16*)alloc((size_t)3 * 1536 * 512 * 2);
    __hip_bfloat16* wo_bf   = (__hip_bfloat16*)alloc((size_t)512 * 512 * 2);
    __hip_bfloat16* xemb_bf = (__hip_bfloat16*)alloc((size_t)TT * BB * EE * 2);
    float* KV    = (float*)alloc((size_t)4096 * 1024 * 4);
    float* GI0   = (float*)alloc((size_t)1280 * 1536 * 4);
    float* GH    = (float*)alloc((size_t)3 * 64 * 1536 * 4);
    float* GIbuf = (float*)alloc((size_t)64 * 1536 * 4);
    float* hf    = (float*)alloc((size_t)3 * 64 * 512 * 4);
    __hip_bfloat16* hb     = (__hip_bfloat16*)alloc((size_t)3 * 64 * 512 * 2);
    float* qbuf  = (float*)alloc((size_t)64 * 512 * 4);
    __hip_bfloat16* ctx_bf = (__hip_bfloat16*)alloc((size_t)64 * 512 * 2);
    __hip_bfloat16* AO     = (__hip_bfloat16*)alloc((size_t)1280 * 512 * 2);

    // ---- setup: converts / gathers / init ----
    auto cvt = [&](const float* src, __hip_bfloat16* dst, int n) {
        f2bf_kernel<<<(n + 255) / 256, 256, 0, stream>>>(src, dst, n);
    };
    cvt(fc_w, fcw_bf, VV * HH);
    cvt(enc, enc_bf, BB * SS * HH);
    cvt(in_proj_w, inp_bf, 1536 * 512);
    cvt(w_ih, wih_bf, 3 * 1536 * 512);
    cvt(w_hh, whh_bf, 3 * 1536 * 512);
    cvt(out_proj_w, wo_bf, 512 * 512);
    gather_emb_kernel<<<(TT * BB * EE) / 256, 256, 0, stream>>>(emb_tab, cap, xemb_bf);
    zero_h_kernel<<<(3 * 64 * 512) / 256, 256, 0, stream>>>(hf, hb, 3 * 64 * 512);

    // KV = enc @ [Wk;Wv]^T + [bk;bv]   (4096 x 1024, K=512)
    gemm_bt_kernel<<<dim3(64, 16, 1), 256, 0, stream>>>(
        enc_bf, inp_bf + 512 * 512, in_proj_b + 512, KV, nullptr,
        512, 1024, 1, 0, 0, 0, 0);

    // GI0 = xemb @ Wih0^T   (1280 x 1536, no bias)
    gemm_bt_kernel<<<dim3(20, 24, 1), 256, 0, stream>>>(
        xemb_bf, wih_bf, nullptr, GI0, nullptr,
        512, 1536, 1, 0, 0, 0, 0);

    // ---- recurrence ----
    for (int t = 0; t < TT; ++t) {
        // GH[l] = h[l] @ Whh[l]^T for l=0..2 (batched over z)
        gemm_bt_kernel<<<dim3(1, 24, 3), 256, 0, stream>>>(
            hb, whh_bf, nullptr, GH, nullptr,
            512, 1536, 1, 0, (long)64 * 512, (long)1536 * 512, (long)64 * 1536);

        // layer 0
        gru_combine_kernel<<<128, 256, 0, stream>>>(
            GI0 + (size_t)t * 64 * 1536, GH, b_ih, b_hh, hf, hb);
        // layer 1
        gemm_bt_kernel<<<dim3(1, 24, 1), 256, 0, stream>>>(
            hb, wih_bf + (size_t)1 * 1536 * 512, nullptr, GIbuf, nullptr,
            512, 1536, 1, 0, 0, 0, 0);
        gru_combine_kernel<<<128, 256, 0, stream>>>(
            GIbuf, GH + 64 * 1536, b_ih + 1536, b_hh + 1536, hf + 64 * 512, hb + 64 * 512);
        // layer 2
        gemm_bt_kernel<<<dim3(1, 24, 1), 256, 0, stream>>>(
            hb + 64 * 512, wih_bf + (size_t)2 * 1536 * 512, nullptr, GIbuf, nullptr,
            512, 1536, 1, 0, 0, 0, 0);
        gru_combine_kernel<<<128, 256, 0, stream>>>(
            GIbuf, GH + 2 * 64 * 1536, b_ih + 2 * 1536, b_hh + 2 * 1536,
            hf + 2 * 64 * 512, hb + 2 * 64 * 512);

        // q = h2 @ Wq^T + bq   (64 x 512)
        gemm_bt_kernel<<<dim3(1, 8, 1), 256, 0, stream>>>(
            hb + 2 * 64 * 512, inp_bf, in_proj_b, qbuf, nullptr,
            512, 512, 1, 0, 0, 0, 0);

        // attention -> ctx (bf16)
        attn_kernel<<<512, 64, 0, stream>>>(qbuf, KV, ctx_bf);

        // AO[b*T+t] = ctx @ Wo^T + bo  (bf16 out, row remap b -> b*T+t)
        gemm_bt_kernel<<<dim3(1, 8, 1), 256, 0, stream>>>(
            ctx_bf, wo_bf, out_proj_b, nullptr, AO,
            512, 512, TT, t, 0, 0, 0);
    }

    // logits = AO @ fc_w^T + fc_b   (1280 x 32000) -> d_out (B,T,V)
    gemm_bt_kernel<<<dim3(20, 500, 1), 256, 0, stream>>>(
        AO, fcw_bf, fc_b, out, nullptr,
        512, VV, 1, 0, 0, 0, 0);
}